// Round 14
// baseline (1050.064 us; speedup 1.0000x reference)
//
#include <hip/hip_runtime.h>
#include <stdint.h>

// BitNet b1.58 column-parallel linear:
//   y[m,n] = (sum_k qx[m,k]*qw[n,k]) * inv_sx[m] * inv_sw + bias[n]
// M=8192 (B*S), N=16384 (D_OUT), K=4096 (D_IN)

#define M_ROWS 8192
#define N_COLS 16384
#define K_DIM  4096
#define NT     (K_DIM / 64)   // 64 K-steps of 64 bytes

typedef int v4i __attribute__((ext_vector_type(4)));

// ---------------- workspace layout ----------------
#define WS_PARTIALS 0
#define WS_PARAMS   8192
#define WS_INVSX    8448
#define WS_QX       41216
#define WS_QW       (41216 + 33554432)
#define WS_NEED     ((size_t)WS_QW + 67108864)

// ---------------- activation quant: per-row int8 absmax ----------------
__device__ __forceinline__ int quant_act1(float v, float s) {
    float q = rintf(v * s);               // round-half-even, matches jnp.round
    q = fminf(127.0f, fmaxf(-128.0f, q));
    return (int)q;
}

__global__ __launch_bounds__(256) void act_quant_kernel(const float* __restrict__ x,
                                                        int8_t* __restrict__ qx,
                                                        float* __restrict__ inv_sx) {
    const int row = blockIdx.x;
    const int t = threadIdx.x;
    const float4* xr = (const float4*)(x + (size_t)row * K_DIM);

    float4 v[4];
    float m = 0.0f;
#pragma unroll
    for (int i = 0; i < 4; ++i) {
        v[i] = xr[t + 256 * i];
        m = fmaxf(m, fmaxf(fmaxf(fabsf(v[i].x), fabsf(v[i].y)),
                           fmaxf(fabsf(v[i].z), fabsf(v[i].w))));
    }
#pragma unroll
    for (int off = 32; off > 0; off >>= 1) m = fmaxf(m, __shfl_xor(m, off));
    __shared__ float wm[4];
    if ((t & 63) == 0) wm[t >> 6] = m;
    __syncthreads();
    m = fmaxf(fmaxf(wm[0], wm[1]), fmaxf(wm[2], wm[3]));
    m = fmaxf(m, 1e-5f);                  // clip(max, EPS)
    const float scale = 127.0f / m;
    if (t == 0) inv_sx[row] = 1.0f / scale;

    int* qr = (int*)(qx + (size_t)row * K_DIM);
#pragma unroll
    for (int i = 0; i < 4; ++i) {
        int b0 = quant_act1(v[i].x, scale) & 255;
        int b1 = quant_act1(v[i].y, scale) & 255;
        int b2 = quant_act1(v[i].z, scale) & 255;
        int b3 = quant_act1(v[i].w, scale) & 255;
        qr[t + 256 * i] = b0 | (b1 << 8) | (b2 << 16) | (b3 << 24);
    }
}

// ---------------- weight abs-sum (deterministic two-stage) ----------------
__global__ __launch_bounds__(256) void wabs_partial_kernel(const float* __restrict__ w,
                                                           float* __restrict__ partials) {
    const int t = threadIdx.x;
    const size_t base = (size_t)blockIdx.x * 8192;   // float4 units
    const float4* w4 = (const float4*)w;
    float s = 0.0f;
#pragma unroll 8
    for (int i = 0; i < 32; ++i) {
        float4 v = w4[base + (size_t)i * 256 + t];
        s += fabsf(v.x) + fabsf(v.y) + fabsf(v.z) + fabsf(v.w);
    }
#pragma unroll
    for (int off = 32; off > 0; off >>= 1) s += __shfl_xor(s, off);
    __shared__ float wp[4];
    if ((t & 63) == 0) wp[t >> 6] = s;
    __syncthreads();
    if (t == 0) partials[blockIdx.x] = (wp[0] + wp[1]) + (wp[2] + wp[3]);
}

__global__ __launch_bounds__(256) void wfinal_kernel(const float* __restrict__ partials,
                                                     float* __restrict__ params) {
    __shared__ double sh[256];
    const int t = threadIdx.x;
    double s = 0.0;
    for (int i = t; i < 2048; i += 256) s += (double)partials[i];
    sh[t] = s;
    __syncthreads();
    for (int off = 128; off > 0; off >>= 1) {
        if (t < off) sh[t] += sh[t + off];
        __syncthreads();
    }
    if (t == 0) {
        float mean = (float)(sh[0] / 67108864.0);
        mean = fmaxf(mean, 1e-5f);        // clip(mean, EPS)
        float scale = 1.0f / mean;        // scale_w
        params[0] = scale;
        params[1] = 1.0f / scale;         // inv_sw
    }
}

// ---------------- weight quant: per-tensor ternary ----------------
__device__ __forceinline__ int quant_w1(float v, float s) {
    float q = rintf(v * s);
    q = fminf(1.0f, fmaxf(-1.0f, q));
    return (int)q;
}

__global__ __launch_bounds__(256) void w_quant_kernel(const float* __restrict__ w,
                                                      int8_t* __restrict__ qw,
                                                      const float* __restrict__ params) {
    const float scale = params[0];
    const int stride = gridDim.x * 256;
    const float4* w4 = (const float4*)w;
    int* q4 = (int*)qw;
    for (int g = blockIdx.x * 256 + threadIdx.x; g < 16777216; g += stride) {
        float4 v = w4[g];
        int b0 = quant_w1(v.x, scale) & 255;
        int b1 = quant_w1(v.y, scale) & 255;
        int b2 = quant_w1(v.z, scale) & 255;
        int b3 = quant_w1(v.w, scale) & 255;
        q4[g] = b0 | (b1 << 8) | (b2 << 16) | (b3 << 24);
    }
}

// ---------------- int8 GEMM: SELF-PIPELINED single-wave blocks, zero barriers ----
// R13 (barrier-free) failed because each step was internally serial (reads->lgkm0->MFMA).
// Fix: register-double-buffer the fragments so step t's 12 ds_reads (for tile t+1)
// execute on the LDS pipe UNDER step t's 32-MFMA cluster. Counted waits only:
//   step t: { vmcnt(0) [tile t+1's GLDs, issued 1 step (~650cy) ago -> near-free] |
//             12 ds_read(slot (t+1)&1 -> other set) | lgkm(12) [this step's set ready] |
//             GLD12(t+2 -> slot t&1, reads just proven drained) | 32 MFMA }
// No s_barrier anywhere; 6 blocks/CU (ring-2 x 12KB = 24KB each) drift freely.
// Frag sets P/Q statically named (rule #20): 96 VGPR + 128 acc fits 256 (R4-proven).
// Staging/swizzle/fragment-offset/epilogue byte-identical to R13 (passed, 0 conflicts).
__global__ __launch_bounds__(64, 2) void gemm_i8_kernel(const int8_t* __restrict__ qx,
                                                        const int8_t* __restrict__ qw,
                                                        const float* __restrict__ inv_sx,
                                                        const float* __restrict__ params,
                                                        const float* __restrict__ bias,
                                                        float* __restrict__ y) {
    __shared__ __align__(16) int8_t lds[2][12288];   // per slot: A[128][64] + B[64][64]
    int8_t* L = &lds[0][0];

    const int lane = threadIdx.x;     // 0..63 (block == one wave)

    // XCD-aware bijective swizzle: 16384 blocks, 8 XCDs; bn-fast (A panel L2-resident)
    const int bid = blockIdx.x;
    const int swz = (bid & 7) * 2048 + (bid >> 3);
    const int bn = swz & 255;         // 256 n-tiles of 64
    const int bm = swz >> 8;          // 64 m-tiles of 128

    const size_t arow0 = (size_t)bm * 128;
    const size_t bcol0 = (size_t)bn * 64;

    // staging addressing: per GLD instr, 64 lanes x 16B = 16 rows x 64B (linear LDS)
    const int r16 = lane >> 2;                        // 0..15
    const int kc0 = (lane & 3) ^ ((r16 >> 1) & 3);    // swizzled k-slot (involution)
    const int8_t* gA = qx + (arow0 + r16) * K_DIM + kc0 * 16;
    const int8_t* gB = qw + (bcol0 + r16) * K_DIM + kc0 * 16;

#define GLD(g, l)                                                                        \
    __builtin_amdgcn_global_load_lds((const __attribute__((address_space(1))) void*)(g), \
                                     (__attribute__((address_space(3))) void*)(l), 16, 0, 0)

// stage K-step ks into slot S: A 8 instrs (128 rows), B 4 instrs (64 rows)
#define GLD12(ks, S)                                                                     \
    do {                                                                                 \
        const size_t _o = (size_t)(ks) * 64;                                             \
        _Pragma("unroll") for (int _g = 0; _g < 8; ++_g)                                 \
            GLD(gA + _o + (size_t)_g * (16 * K_DIM), L + (S) * 12288 + _g * 1024);       \
        _Pragma("unroll") for (int _h = 0; _h < 4; ++_h)                                 \
            GLD(gB + _o + (size_t)_h * (16 * K_DIM), L + (S) * 12288 + 8192 + _h * 1024);\
    } while (0)

    // fragment ds_read offsets (within one 12KB slot) — verified 16x16x64 layout
    const int ksub = lane >> 4;       // 16B k-chunk 0..3
    const int lrow = lane & 15;
    int aoff[8], boff[4];
#pragma unroll
    for (int i = 0; i < 8; ++i) {
        int ra = i * 16 + lrow;
        aoff[i] = ra * 64 + ((ksub ^ ((ra >> 1) & 3)) << 4);
    }
#pragma unroll
    for (int j = 0; j < 4; ++j) {
        int rb = j * 16 + lrow;
        boff[j] = 8192 + rb * 64 + ((ksub ^ ((rb >> 1) & 3)) << 4);
    }

    v4i acc[8][4];
#pragma unroll
    for (int i = 0; i < 8; ++i)
#pragma unroll
        for (int j = 0; j < 4; ++j) acc[i][j] = (v4i){0, 0, 0, 0};

    // register-double-buffered fragment sets (static names)
    v4i aP[8], bP[4], aQ[8], bQ[4];

#define RD12(S, A_, B_)                                                        \
    do {                                                                       \
        const int8_t* _p = L + (S) * 12288;                                    \
        _Pragma("unroll") for (int _i = 0; _i < 8; ++_i)                       \
            A_[_i] = *(const v4i*)(_p + aoff[_i]);                             \
        _Pragma("unroll") for (int _j = 0; _j < 4; ++_j)                       \
            B_[_j] = *(const v4i*)(_p + boff[_j]);                             \
    } while (0)

#define MFMA32(A_, B_)                                                         \
    do {                                                                       \
        __builtin_amdgcn_s_setprio(1);                                         \
        _Pragma("unroll") for (int _i = 0; _i < 8; ++_i)                       \
            _Pragma("unroll") for (int _j = 0; _j < 4; ++_j)                   \
                acc[_i][_j] = __builtin_amdgcn_mfma_i32_16x16x64_i8(           \
                    A_[_i], B_[_j], acc[_i][_j], 0, 0, 0);                     \
        __builtin_amdgcn_s_setprio(0);                                         \
    } while (0)

#define VM0()                                                    \
    do {                                                         \
        asm volatile("s_waitcnt vmcnt(0)" ::: "memory");         \
        __builtin_amdgcn_sched_barrier(0);                       \
    } while (0)
#define VM12()                                                   \
    do {                                                         \
        asm volatile("s_waitcnt vmcnt(12)" ::: "memory");        \
        __builtin_amdgcn_sched_barrier(0);                       \
    } while (0)
#define LGKM12()                                                 \
    do {                                                         \
        asm volatile("s_waitcnt lgkmcnt(12)" ::: "memory");      \
        __builtin_amdgcn_sched_barrier(0);                       \
    } while (0)
#define LGKM0()                                                  \
    do {                                                         \
        asm volatile("s_waitcnt lgkmcnt(0)" ::: "memory");       \
        __builtin_amdgcn_sched_barrier(0);                       \
    } while (0)

    // prologue: stage tiles 0,1; vmcnt(12) proves tile 0; preload set P (tile 0)
    GLD12(0, 0);
    GLD12(1, 1);
    VM12();
    RD12(0, aP, bP);

    // main loop: 31 iters x 2 steps (t=0..61); stages tiles 2..63
#pragma unroll 1
    for (int j = 0; j < 31; ++j) {
        const int tb = 2 * j;
        // even step t=2j: compute P (tile t), prefetch Q (tile t+1, slot 1)
        VM0();                       // tile t+1's GLDs landed (issued last step)
        RD12(1, aQ, bQ);             // reads run under MFMA below
        LGKM12();                    // set P complete (issued at t-1)
        GLD12(tb + 2, 0);            // slot 0: P-reads just proven drained
        MFMA32(aP, bP);
        // odd step t=2j+1: compute Q, prefetch P (tile t+2, slot 0)
        VM0();                       // tile t+2 landed
        RD12(0, aP, bP);
        LGKM12();                    // set Q complete
        GLD12(tb + 3, 1);            // slot 1: Q-reads proven drained
        MFMA32(aQ, bQ);
    }
    // tail: t=62 (tile 62 in P), t=63 (tile 63 in Q)
    VM0();                           // tile 63 landed (staged at t=61)
    RD12(1, aQ, bQ);                 // tile 63
    LGKM12();                        // set P (tile 62) ready
    MFMA32(aP, bP);
    LGKM0();                         // set Q ready
    MFMA32(aQ, bQ);

    // epilogue: y = acc * inv_sx[row] * inv_sw + bias[col]  (verified 16x16 C/D layout)
    const float invsw = params[1];
    const int rl = (lane >> 4) * 4;
#pragma unroll
    for (int i = 0; i < 8; ++i) {
        const int grow_base = (int)arow0 + i * 16 + rl;
        float isx[4];
#pragma unroll
        for (int r = 0; r < 4; ++r) isx[r] = inv_sx[grow_base + r] * invsw;
#pragma unroll
        for (int j = 0; j < 4; ++j) {
            const int gcol = (int)bcol0 + j * 16 + lrow;
            const float bb = bias[gcol];
#pragma unroll
            for (int r = 0; r < 4; ++r) {
                y[(size_t)(grow_base + r) * N_COLS + gcol] =
                    (float)acc[i][j][r] * isx[r] + bb;
            }
        }
    }
#undef GLD
#undef GLD12
#undef RD12
#undef MFMA32
#undef VM0
#undef VM12
#undef LGKM12
#undef LGKM0
}

// ---------------- launch ----------------
extern "C" void kernel_launch(void* const* d_in, const int* in_sizes, int n_in,
                              void* d_out, int out_size, void* d_ws, size_t ws_size,
                              hipStream_t stream) {
    const float* x    = (const float*)d_in[0];
    const float* wt   = (const float*)d_in[1];
    const float* bias = (const float*)d_in[2];
    float* y = (float*)d_out;

    if (ws_size < WS_NEED) return;

    char* ws = (char*)d_ws;
    float* partials = (float*)(ws + WS_PARTIALS);
    float* params   = (float*)(ws + WS_PARAMS);
    float* inv_sx   = (float*)(ws + WS_INVSX);
    int8_t* qx = (int8_t*)(ws + WS_QX);
    int8_t* qw = (int8_t*)(ws + WS_QW);

    hipLaunchKernelGGL(act_quant_kernel,   dim3(8192), dim3(256), 0, stream, x, qx, inv_sx);
    hipLaunchKernelGGL(wabs_partial_kernel,dim3(2048), dim3(256), 0, stream, wt, partials);
    hipLaunchKernelGGL(wfinal_kernel,      dim3(1),    dim3(256), 0, stream, partials, params);
    hipLaunchKernelGGL(w_quant_kernel,     dim3(4096), dim3(256), 0, stream, wt, qw, params);
    hipLaunchKernelGGL(gemm_i8_kernel,     dim3(16384), dim3(64), 0, stream,
                       qx, qw, inv_sx, params, bias, y);
}

// Round 15
// 707.970 us; speedup vs baseline: 1.4832x; 1.4832x over previous
//
#include <hip/hip_runtime.h>
#include <stdint.h>

// BitNet b1.58 column-parallel linear:
//   y[m,n] = (sum_k qx[m,k]*qw[n,k]) * inv_sx[m] * inv_sw + bias[n]
// M=8192 (B*S), N=16384 (D_OUT), K=4096 (D_IN)

#define M_ROWS 8192
#define N_COLS 16384
#define K_DIM  4096
#define NT     (K_DIM / 64)   // 64 K-steps of 64 bytes

typedef int v4i __attribute__((ext_vector_type(4)));

// ---------------- workspace layout ----------------
#define WS_PARTIALS 0
#define WS_PARAMS   8192
#define WS_INVSX    8448
#define WS_QX       41216
#define WS_QW       (41216 + 33554432)
#define WS_NEED     ((size_t)WS_QW + 67108864)

// ---------------- fused: activation quant (blocks 0..8191) + weight abs-sum partials
// (blocks 8192..10239). Independent memory-bound passes overlapped in one launch.
__device__ __forceinline__ int quant_act1(float v, float s) {
    float q = rintf(v * s);               // round-half-even, matches jnp.round
    q = fminf(127.0f, fmaxf(-128.0f, q));
    return (int)q;
}

__global__ __launch_bounds__(256) void fused_quant_kernel(const float* __restrict__ x,
                                                          int8_t* __restrict__ qx,
                                                          float* __restrict__ inv_sx,
                                                          const float* __restrict__ w,
                                                          float* __restrict__ partials) {
    const int t = threadIdx.x;
    if (blockIdx.x < 8192) {
        // ---- activation quant: per-row int8 absmax ----
        const int row = blockIdx.x;
        const float4* xr = (const float4*)(x + (size_t)row * K_DIM);

        float4 v[4];
        float m = 0.0f;
#pragma unroll
        for (int i = 0; i < 4; ++i) {
            v[i] = xr[t + 256 * i];
            m = fmaxf(m, fmaxf(fmaxf(fabsf(v[i].x), fabsf(v[i].y)),
                               fmaxf(fabsf(v[i].z), fabsf(v[i].w))));
        }
#pragma unroll
        for (int off = 32; off > 0; off >>= 1) m = fmaxf(m, __shfl_xor(m, off));
        __shared__ float wm[4];
        if ((t & 63) == 0) wm[t >> 6] = m;
        __syncthreads();
        m = fmaxf(fmaxf(wm[0], wm[1]), fmaxf(wm[2], wm[3]));
        m = fmaxf(m, 1e-5f);              // clip(max, EPS)
        const float scale = 127.0f / m;
        if (t == 0) inv_sx[row] = 1.0f / scale;

        int* qr = (int*)(qx + (size_t)row * K_DIM);
#pragma unroll
        for (int i = 0; i < 4; ++i) {
            int b0 = quant_act1(v[i].x, scale) & 255;
            int b1 = quant_act1(v[i].y, scale) & 255;
            int b2 = quant_act1(v[i].z, scale) & 255;
            int b3 = quant_act1(v[i].w, scale) & 255;
            qr[t + 256 * i] = b0 | (b1 << 8) | (b2 << 16) | (b3 << 24);
        }
    } else {
        // ---- weight abs-sum partial (deterministic) ----
        const int pb = blockIdx.x - 8192;             // 0..2047
        const size_t base = (size_t)pb * 8192;        // float4 units
        const float4* w4 = (const float4*)w;
        float s = 0.0f;
#pragma unroll 8
        for (int i = 0; i < 32; ++i) {
            float4 v = w4[base + (size_t)i * 256 + t];
            s += fabsf(v.x) + fabsf(v.y) + fabsf(v.z) + fabsf(v.w);
        }
#pragma unroll
        for (int off = 32; off > 0; off >>= 1) s += __shfl_xor(s, off);
        __shared__ float wp[4];
        if ((t & 63) == 0) wp[t >> 6] = s;
        __syncthreads();
        if (t == 0) partials[pb] = (wp[0] + wp[1]) + (wp[2] + wp[3]);
    }
}

__global__ __launch_bounds__(256) void wfinal_kernel(const float* __restrict__ partials,
                                                     float* __restrict__ params) {
    __shared__ double sh[256];
    const int t = threadIdx.x;
    double s = 0.0;
    for (int i = t; i < 2048; i += 256) s += (double)partials[i];
    sh[t] = s;
    __syncthreads();
    for (int off = 128; off > 0; off >>= 1) {
        if (t < off) sh[t] += sh[t + off];
        __syncthreads();
    }
    if (t == 0) {
        float mean = (float)(sh[0] / 67108864.0);
        mean = fmaxf(mean, 1e-5f);        // clip(mean, EPS)
        float scale = 1.0f / mean;        // scale_w
        params[0] = scale;
        params[1] = 1.0f / scale;         // inv_sw
    }
}

// ---------------- weight quant: per-tensor ternary ----------------
__device__ __forceinline__ int quant_w1(float v, float s) {
    float q = rintf(v * s);
    q = fminf(1.0f, fmaxf(-1.0f, q));
    return (int)q;
}

__global__ __launch_bounds__(256) void w_quant_kernel(const float* __restrict__ w,
                                                      int8_t* __restrict__ qw,
                                                      const float* __restrict__ params) {
    const float scale = params[0];
    const int stride = gridDim.x * 256;
    const float4* w4 = (const float4*)w;
    int* q4 = (int*)qw;
    for (int g = blockIdx.x * 256 + threadIdx.x; g < 16777216; g += stride) {
        float4 v = w4[g];
        int b0 = quant_w1(v.x, scale) & 255;
        int b1 = quant_w1(v.y, scale) & 255;
        int b2 = quant_w1(v.z, scale) & 255;
        int b3 = quant_w1(v.w, scale) & 255;
        q4[g] = b0 | (b1 << 8) | (b2 << 16) | (b3 << 24);
    }
}

// ---------------- int8 GEMM: 256x128 tile, 4 waves, 3-slot ring, 2 BLOCKS/CU ----
// (R9 — best verified: 574us, MfmaUtil 43.6%, 0 bank conflicts. Restored verbatim.)
// m114 mechanism: two independent co-resident blocks per CU (LDS 72KB x 2 <= 160KB,
// regs <= 256/wave incl AGPR via launch_bounds(256,2)) provide MFMA<->LDS overlap —
// when one block's waves are in their read/barrier phase, the other block's waves
// feed the MFMA pipe.
// 4 waves (2M x 2N), per-wave 128x64, mfma_i32_16x16x64_i8 (verified layout).
// 3-slot ring (slot = t%3), stage-2-ahead, 6 GLD/thread/step (4 A + 2 B).
// Per step t: { 12 ds_read slot t%3 | GLD6(t+2 -> (t+2)%3) | 32 MFMA |
//              vmcnt(6) [proves K(t+1)] | s_barrier [publishes slot (t+1)%3] }.
// Slot-overwrite safety: GLD(t+2) targets slot (t-1)%3 whose reads drained before the
// end-of-(t-1) barrier (MFMA reg deps force lgkm completion pre-barrier).
// 16B-chunk XOR swizzle on global source + ds_read addr (rounds 1-14: 0 conflicts).
__global__ __launch_bounds__(256, 2) void gemm_i8_kernel(const int8_t* __restrict__ qx,
                                                         const int8_t* __restrict__ qw,
                                                         const float* __restrict__ inv_sx,
                                                         const float* __restrict__ params,
                                                         const float* __restrict__ bias,
                                                         float* __restrict__ y) {
    __shared__ __align__(16) int8_t lds[3][24576];   // per slot: A[256][64] + B[128][64]
    int8_t* L = &lds[0][0];

    const int tid = threadIdx.x;
    const int lane = tid & 63;
    const int w = tid >> 6;           // wave 0..3
    const int wr = w >> 1;            // 0..1  (M half)
    const int wc = w & 1;             // 0..1  (N half)
    const int wbase = w * 1024;       // wave-uniform LDS staging base

    // XCD-aware bijective swizzle: 4096 blocks, 8 XCDs
    const int bid = blockIdx.x;
    const int swz = (bid & 7) * 512 + (bid >> 3);
    const int bn = swz & 127;         // 128 n-blocks (fast: consecutive share A-panel)
    const int bm = swz >> 7;          // 32 m-blocks

    const size_t arow0 = (size_t)bm * 256;
    const size_t bcol0 = (size_t)bn * 128;

    // staging: A 1024 chunks of 16B (4/thread, row stride 64), B 512 chunks (2/thread)
    const int r0 = tid >> 2;                       // 0..63
    const int kc0 = (tid & 3) ^ ((r0 >> 1) & 3);   // swizzled k-slot (involution)
    const int8_t* gA = qx + (arow0 + r0) * K_DIM + kc0 * 16;
    const int8_t* gB = qw + (bcol0 + r0) * K_DIM + kc0 * 16;

#define GLD(g, l)                                                                        \
    __builtin_amdgcn_global_load_lds((const __attribute__((address_space(1))) void*)(g), \
                                     (__attribute__((address_space(3))) void*)(l), 16, 0, 0)

// stage K-step ks into slot S: 4 A chunks + 2 B chunks per thread
#define GLD6(ks, S)                                                                      \
    do {                                                                                 \
        const size_t _o = (size_t)(ks) * 64;                                             \
        _Pragma("unroll") for (int _g = 0; _g < 4; ++_g)                                 \
            GLD(gA + _o + (size_t)_g * (64 * K_DIM),                                     \
                L + (S) * 24576 + _g * 4096 + wbase);                                    \
        _Pragma("unroll") for (int _h = 0; _h < 2; ++_h)                                 \
            GLD(gB + _o + (size_t)_h * (64 * K_DIM),                                     \
                L + (S) * 24576 + 16384 + _h * 4096 + wbase);                            \
    } while (0)

    // fragment ds_read offsets (within one 24KB slot) — verified 16x16x64 layout
    const int ksub = lane >> 4;       // 16B k-chunk 0..3
    const int lrow = lane & 15;
    int aoff[8], boff[4];
#pragma unroll
    for (int i = 0; i < 8; ++i) {
        int ra = wr * 128 + i * 16 + lrow;
        aoff[i] = ra * 64 + ((ksub ^ ((ra >> 1) & 3)) << 4);
    }
#pragma unroll
    for (int j = 0; j < 4; ++j) {
        int rb = wc * 64 + j * 16 + lrow;
        boff[j] = 16384 + rb * 64 + ((ksub ^ ((rb >> 1) & 3)) << 4);
    }

    v4i acc[8][4];
#pragma unroll
    for (int i = 0; i < 8; ++i)
#pragma unroll
        for (int j = 0; j < 4; ++j) acc[i][j] = (v4i){0, 0, 0, 0};

#define BARR()                                                                 \
    do {                                                                       \
        __builtin_amdgcn_s_barrier();                                          \
        __builtin_amdgcn_sched_barrier(0);                                     \
    } while (0)
#define VM(NSTR) asm volatile("s_waitcnt vmcnt(" NSTR ")" ::: "memory")

// One K-step: read 12 frags from slot CS, stage FKS (if STG), 32 MFMA, wait, barrier.
#define STEP(CS, FKS, FSL, STG, VMSTMT, DOBAR)                                 \
    do {                                                                       \
        const int8_t* _p = L + (CS) * 24576;                                   \
        v4i a[8], b[4];                                                        \
        _Pragma("unroll") for (int _i = 0; _i < 8; ++_i)                       \
            a[_i] = *(const v4i*)(_p + aoff[_i]);                              \
        _Pragma("unroll") for (int _j = 0; _j < 4; ++_j)                       \
            b[_j] = *(const v4i*)(_p + boff[_j]);                              \
        if (STG) GLD6(FKS, FSL);                                               \
        __builtin_amdgcn_s_setprio(1);                                         \
        _Pragma("unroll") for (int _i = 0; _i < 8; ++_i)                       \
            _Pragma("unroll") for (int _j = 0; _j < 4; ++_j)                   \
                acc[_i][_j] = __builtin_amdgcn_mfma_i32_16x16x64_i8(           \
                    a[_i], b[_j], acc[_i][_j], 0, 0, 0);                       \
        __builtin_amdgcn_s_setprio(0);                                         \
        VMSTMT;                                                                \
        if (DOBAR) BARR();                                                     \
    } while (0)

    // prologue: stage K0->s0, K1->s1; vmcnt(6) proves K0; barrier publishes s0
    GLD6(0, 0);
    GLD6(1, 1);
    VM("6");
    BARR();

    // main loop: j=0..19, K-steps 3j..3j+2 (t=0..59), staging t+2 (slots 2,0,1)
#pragma unroll 1
    for (int j = 0; j < 20; ++j) {
        const int tb = 3 * j;
        STEP(0, tb + 2, 2, 1, VM("6"), 1);   // t=3j: proves K(t+1)
        STEP(1, tb + 3, 0, 1, VM("6"), 1);
        STEP(2, tb + 4, 1, 1, VM("6"), 1);
    }
    // tail: t=60..63 (slots 0,1,2,0); K62 staged at t=60, K63 at t=61
    STEP(0, 62, 2, 1, VM("6"), 1);     // t=60: proves K61
    STEP(1, 63, 0, 1, VM("6"), 1);     // t=61: proves K62
    STEP(2, 0, 0, 0, VM("0"), 1);      // t=62: proves K63
    STEP(0, 0, 0, 0, (void)0, 0);      // t=63

    // epilogue: y = acc * inv_sx[row] * inv_sw + bias[col]  (verified 16x16 C/D layout)
    const float invsw = params[1];
    const int rl = (lane >> 4) * 4;
#pragma unroll
    for (int i = 0; i < 8; ++i) {
        const int grow_base = (int)arow0 + wr * 128 + i * 16 + rl;
        float isx[4];
#pragma unroll
        for (int r = 0; r < 4; ++r) isx[r] = inv_sx[grow_base + r] * invsw;
#pragma unroll
        for (int j = 0; j < 4; ++j) {
            const int gcol = (int)bcol0 + wc * 64 + j * 16 + lrow;
            const float bb = bias[gcol];
#pragma unroll
            for (int r = 0; r < 4; ++r) {
                y[(size_t)(grow_base + r) * N_COLS + gcol] =
                    (float)acc[i][j][r] * isx[r] + bb;
            }
        }
    }
#undef GLD
#undef GLD6
#undef BARR
#undef VM
#undef STEP
}

// ---------------- launch ----------------
extern "C" void kernel_launch(void* const* d_in, const int* in_sizes, int n_in,
                              void* d_out, int out_size, void* d_ws, size_t ws_size,
                              hipStream_t stream) {
    const float* x    = (const float*)d_in[0];
    const float* wt   = (const float*)d_in[1];
    const float* bias = (const float*)d_in[2];
    float* y = (float*)d_out;

    if (ws_size < WS_NEED) return;

    char* ws = (char*)d_ws;
    float* partials = (float*)(ws + WS_PARTIALS);
    float* params   = (float*)(ws + WS_PARAMS);
    float* inv_sx   = (float*)(ws + WS_INVSX);
    int8_t* qx = (int8_t*)(ws + WS_QX);
    int8_t* qw = (int8_t*)(ws + WS_QW);

    hipLaunchKernelGGL(fused_quant_kernel, dim3(10240), dim3(256), 0, stream,
                       x, qx, inv_sx, wt, partials);
    hipLaunchKernelGGL(wfinal_kernel,      dim3(1),    dim3(256), 0, stream, partials, params);
    hipLaunchKernelGGL(w_quant_kernel,     dim3(4096), dim3(256), 0, stream, wt, qw, params);
    hipLaunchKernelGGL(gemm_i8_kernel,     dim3(4096), dim3(256), 0, stream,
                       qx, qw, inv_sx, params, bias, y);
}